// Round 1
// baseline (368.158 us; speedup 1.0000x reference)
//
#include <hip/hip_runtime.h>
#include <hip/hip_bf16.h>

typedef __attribute__((ext_vector_type(8))) short bf16x8;
typedef __attribute__((ext_vector_type(4))) float f32x4;

#define GLOBAL_CAST(p) (const __attribute__((address_space(1))) void*)(p)
#define LDS_CAST(p)    (__attribute__((address_space(3))) void*)(p)

static __device__ __forceinline__ unsigned short f2bf(float f) {
    union { float f; unsigned int u; } v; v.f = f;
    unsigned int u = v.u;
    unsigned int r = (u + 0x7FFFu + ((u >> 16) & 1u)) >> 16;   // RNE
    return (unsigned short)r;
}

// ---------------------------------------------------------------------------
// Kernel 1: per-row scale = max(mean(|w|), eps); q = ternary(w) as bf16 bits.
// One block (256 threads) per output row. q may be nullptr (fallback path).
// ---------------------------------------------------------------------------
__global__ __launch_bounds__(256) void scale_quant_kernel(
    const float* __restrict__ w, float* __restrict__ scale,
    unsigned short* __restrict__ q, int K)
{
    const int row = blockIdx.x;
    const int tid = threadIdx.x;
    const float* wrow = w + (size_t)row * K;

    float s = 0.f;
    const int nvec = K >> 2;
    const float4* wv = (const float4*)wrow;
    for (int i = tid; i < nvec; i += blockDim.x) {
        float4 v = wv[i];
        s += fabsf(v.x) + fabsf(v.y) + fabsf(v.z) + fabsf(v.w);
    }
    // wave reduce (64 lanes)
    #pragma unroll
    for (int off = 32; off > 0; off >>= 1) s += __shfl_down(s, off);

    __shared__ float red[4];
    const int lane = tid & 63, wid = tid >> 6;
    if (lane == 0) red[wid] = s;
    __syncthreads();
    const float total = red[0] + red[1] + red[2] + red[3];
    const float sc = fmaxf(total / (float)K, 1e-6f);
    const float thr = sc * 0.75f;
    if (tid == 0) scale[row] = sc;

    if (q != nullptr) {
        ushort4* qv = (ushort4*)(q + (size_t)row * K);
        for (int i = tid; i < nvec; i += blockDim.x) {
            float4 v = wv[i];
            ushort4 o;
            o.x = (v.x >= thr) ? 0x3F80u : ((v.x <= -thr) ? 0xBF80u : 0u);
            o.y = (v.y >= thr) ? 0x3F80u : ((v.y <= -thr) ? 0xBF80u : 0u);
            o.z = (v.z >= thr) ? 0x3F80u : ((v.z <= -thr) ? 0xBF80u : 0u);
            o.w = (v.w >= thr) ? 0x3F80u : ((v.w <= -thr) ? 0xBF80u : 0u);
            qv[i] = o;
        }
    }
}

// ---------------------------------------------------------------------------
// Kernel 2: x fp32 -> bf16 (RNE), vectorized 8 elems/thread.
// ---------------------------------------------------------------------------
__global__ __launch_bounds__(256) void convert_x_kernel(
    const float* __restrict__ x, unsigned short* __restrict__ xb, long n)
{
    long i = ((long)blockIdx.x * blockDim.x + threadIdx.x) * 8;
    if (i + 8 > n) return;
    float4 a = *(const float4*)(x + i);
    float4 b = *(const float4*)(x + i + 4);
    ushort4 lo, hi;
    lo.x = f2bf(a.x); lo.y = f2bf(a.y); lo.z = f2bf(a.z); lo.w = f2bf(a.w);
    hi.x = f2bf(b.x); hi.y = f2bf(b.y); hi.z = f2bf(b.z); hi.w = f2bf(b.w);
    *(ushort4*)(xb + i)     = lo;
    *(ushort4*)(xb + i + 4) = hi;
}

// ---------------------------------------------------------------------------
// Kernel 3: bf16 GEMM  out[m][n] = scale[n] * sum_k Xb[m][k]*Qb[n][k] + bias[n]
// m97 structure: 128x128 tile, BK=64, 4 waves (2x2), each wave 64x64 via
// 4x4 fragments of mfma_f32_16x16x32_bf16. global_load_lds width=16 with
// both-sides XOR chunk swizzle (linear LDS dest, pre-swizzled global source).
// ---------------------------------------------------------------------------
#define BM 128
#define BN 128
#define BK 64

__global__ __launch_bounds__(256) void ternary_gemm_kernel(
    const unsigned short* __restrict__ Xb,   // [M][K] bf16 bits
    const unsigned short* __restrict__ Qb,   // [N][K] bf16 bits
    const float* __restrict__ scale,         // [N]
    const float* __restrict__ bias,          // [N]
    float* __restrict__ out, int M, int N, int K)
{
    __shared__ __align__(16) unsigned short As[BM * BK];
    __shared__ __align__(16) unsigned short Bs[BN * BK];

    const int tid  = threadIdx.x;
    const int lane = tid & 63;
    const int wid  = tid >> 6;
    const int wr   = wid >> 1;       // 0..1 (M half)
    const int wc   = wid & 1;        // 0..1 (N half)
    const int kh   = lane >> 4;      // 0..3 (k sub-block)
    const int lr   = lane & 15;

    // XCD-bijective block swizzle (grid % 8 == 0 guaranteed by host gate)
    int bid = blockIdx.x;
    const int nwg = gridDim.x;
    if ((nwg & 7) == 0) {
        const int cpx = nwg >> 3;
        bid = (bid & 7) * cpx + (bid >> 3);
    }
    const int nbn = N / BN;
    const int tm = bid / nbn, tn = bid % nbn;
    const size_t arow0 = (size_t)tm * BM;
    const size_t brow0 = (size_t)tn * BN;

    // staging descriptors: 1024 16B-chunks per 128x64 tile, 4 per thread.
    // linear LDS chunk ci -> (row r = ci>>3, slot s = ci&7); the slot holds
    // global chunk c = s ^ (r&7)  (involution: read applies the same XOR).
    int g_row[4], g_col[4], l_off[4];
    #pragma unroll
    for (int it = 0; it < 4; ++it) {
        const int ci = it * 256 + tid;
        const int r = ci >> 3, s = ci & 7;
        g_row[it] = r;
        g_col[it] = (s ^ (r & 7)) * 8;
        l_off[it] = ci * 16;
    }

    f32x4 acc[4][4] = {};

    for (int k0 = 0; k0 < K; k0 += BK) {
        #pragma unroll
        for (int it = 0; it < 4; ++it) {
            const unsigned short* ga = Xb + (arow0 + g_row[it]) * K + k0 + g_col[it];
            const unsigned short* gb = Qb + (brow0 + g_row[it]) * K + k0 + g_col[it];
            __builtin_amdgcn_global_load_lds(GLOBAL_CAST(ga), LDS_CAST((char*)As + l_off[it]), 16, 0, 0);
            __builtin_amdgcn_global_load_lds(GLOBAL_CAST(gb), LDS_CAST((char*)Bs + l_off[it]), 16, 0, 0);
        }
        __syncthreads();   // compiler drains vmcnt before s_barrier

        #pragma unroll
        for (int kk = 0; kk < BK; kk += 32) {
            bf16x8 a[4], b[4];
            const int cbase = (kk >> 3) + kh;
            #pragma unroll
            for (int mf = 0; mf < 4; ++mf) {
                const int row = wr * 64 + mf * 16 + lr;
                const int slot = cbase ^ (row & 7);
                a[mf] = *(const bf16x8*)((const char*)As + row * (BK * 2) + slot * 16);
            }
            #pragma unroll
            for (int nf = 0; nf < 4; ++nf) {
                const int row = wc * 64 + nf * 16 + lr;
                const int slot = cbase ^ (row & 7);
                b[nf] = *(const bf16x8*)((const char*)Bs + row * (BK * 2) + slot * 16);
            }
            #pragma unroll
            for (int mf = 0; mf < 4; ++mf)
                #pragma unroll
                for (int nf = 0; nf < 4; ++nf)
                    acc[mf][nf] = __builtin_amdgcn_mfma_f32_16x16x32_bf16(
                        a[mf], b[nf], acc[mf][nf], 0, 0, 0);
        }
        __syncthreads();
    }

    // epilogue: out = scale[n]*acc + bias[n]
    // D layout: col = lane&15, row = (lane>>4)*4 + r   [m89]
    #pragma unroll
    for (int nf = 0; nf < 4; ++nf) {
        const int gn = (int)brow0 + wc * 64 + nf * 16 + lr;
        const float sc = scale[gn];
        const float bs = bias[gn];
        #pragma unroll
        for (int mf = 0; mf < 4; ++mf) {
            const size_t gm = arow0 + wr * 64 + mf * 16 + kh * 4;
            #pragma unroll
            for (int r = 0; r < 4; ++r)
                out[(gm + r) * (size_t)N + gn] = acc[mf][nf][r] * sc + bs;
        }
    }
}

// ---------------------------------------------------------------------------
// Fallback (insurance if ws too small): fp32 smem-tiled GEMM, quantize on fly.
// ---------------------------------------------------------------------------
__global__ __launch_bounds__(256) void fb_gemm_kernel(
    const float* __restrict__ X, const float* __restrict__ W,
    const float* __restrict__ scale, const float* __restrict__ bias,
    float* __restrict__ out, int M, int N, int K)
{
    __shared__ float xs[16][16];
    __shared__ float qs[16][17];
    const int tx = threadIdx.x & 15, ty = threadIdx.x >> 4;
    const int m = blockIdx.y * 16 + ty;
    const int n = blockIdx.x * 16 + tx;
    const int nrow = blockIdx.x * 16 + ty;   // W row this thread loads
    const int mL = min(m, M - 1);
    const int nrowL = min(nrow, N - 1);
    const float thr = scale[nrowL] * 0.75f;
    float acc = 0.f;
    for (int k0 = 0; k0 < K; k0 += 16) {
        xs[ty][tx] = X[(size_t)mL * K + k0 + tx];
        const float w = W[(size_t)nrowL * K + k0 + tx];
        qs[ty][tx] = (w >= thr) ? 1.f : ((w <= -thr) ? -1.f : 0.f);
        __syncthreads();
        #pragma unroll
        for (int kk = 0; kk < 16; ++kk) acc += xs[ty][kk] * qs[tx][kk];
        __syncthreads();
    }
    if (m < M && n < N) out[(size_t)m * N + n] = scale[n] * acc + bias[n];
}

// ---------------------------------------------------------------------------
extern "C" void kernel_launch(void* const* d_in, const int* in_sizes, int n_in,
                              void* d_out, int out_size, void* d_ws, size_t ws_size,
                              hipStream_t stream)
{
    const float* x    = (const float*)d_in[0];
    const float* w    = (const float*)d_in[1];
    const float* bias = (const float*)d_in[2];
    float* out = (float*)d_out;

    const int N = in_sizes[2];             // OUT
    const int K = in_sizes[1] / N;         // IN
    const int M = in_sizes[0] / K;         // B

    const size_t scaleBytes = (size_t)N * sizeof(float);
    const size_t qOff = (scaleBytes + 255) & ~(size_t)255;
    const size_t xOff = qOff + (size_t)N * K * sizeof(unsigned short);
    const size_t need = xOff + (size_t)M * K * sizeof(unsigned short);

    float* scale = (float*)d_ws;

    const bool fast = (ws_size >= need) &&
                      (M % BM == 0) && (N % BN == 0) && (K % BK == 0) &&
                      (((M / BM) * (N / BN)) % 8 == 0);

    if (fast) {
        unsigned short* q  = (unsigned short*)((char*)d_ws + qOff);
        unsigned short* xb = (unsigned short*)((char*)d_ws + xOff);

        scale_quant_kernel<<<N, 256, 0, stream>>>(w, scale, q, K);

        const long nx = (long)M * K;
        const int cvtBlocks = (int)((nx + 2047) / 2048);
        convert_x_kernel<<<cvtBlocks, 256, 0, stream>>>(x, xb, nx);

        const int grid = (M / BM) * (N / BN);
        ternary_gemm_kernel<<<grid, 256, 0, stream>>>(xb, q, scale, bias, out, M, N, K);
    } else {
        scale_quant_kernel<<<N, 256, 0, stream>>>(w, scale, nullptr, K);
        dim3 g((N + 15) / 16, (M + 15) / 16);
        fb_gemm_kernel<<<g, 256, 0, stream>>>(x, w, scale, bias, out, M, N, K);
    }
}

// Round 2
// 298.956 us; speedup vs baseline: 1.2315x; 1.2315x over previous
//
#include <hip/hip_runtime.h>
#include <hip/hip_bf16.h>

typedef __attribute__((ext_vector_type(8))) short bf16x8;
typedef __attribute__((ext_vector_type(4))) float f32x4;

#define GLOBAL_CAST(p) (const __attribute__((address_space(1))) void*)(p)
#define LDS_CAST(p)    (__attribute__((address_space(3))) void*)(p)

static __device__ __forceinline__ unsigned short f2bf(float f) {
    union { float f; unsigned int u; } v; v.f = f;
    unsigned int u = v.u;
    unsigned int r = (u + 0x7FFFu + ((u >> 16) & 1u)) >> 16;   // RNE
    return (unsigned short)r;
}

// ---------------------------------------------------------------------------
// Kernel 1: per-row scale = max(mean(|w|), eps); q = ternary(w) as bf16 bits.
// ---------------------------------------------------------------------------
__global__ __launch_bounds__(256) void scale_quant_kernel(
    const float* __restrict__ w, float* __restrict__ scale,
    unsigned short* __restrict__ q, int K)
{
    const int row = blockIdx.x;
    const int tid = threadIdx.x;
    const float* wrow = w + (size_t)row * K;

    float s = 0.f;
    const int nvec = K >> 2;
    const float4* wv = (const float4*)wrow;
    for (int i = tid; i < nvec; i += blockDim.x) {
        float4 v = wv[i];
        s += fabsf(v.x) + fabsf(v.y) + fabsf(v.z) + fabsf(v.w);
    }
    #pragma unroll
    for (int off = 32; off > 0; off >>= 1) s += __shfl_down(s, off);

    __shared__ float red[4];
    const int lane = tid & 63, wid = tid >> 6;
    if (lane == 0) red[wid] = s;
    __syncthreads();
    const float total = red[0] + red[1] + red[2] + red[3];
    const float sc = fmaxf(total / (float)K, 1e-6f);
    const float thr = sc * 0.75f;
    if (tid == 0) scale[row] = sc;

    if (q != nullptr) {
        ushort4* qv = (ushort4*)(q + (size_t)row * K);
        for (int i = tid; i < nvec; i += blockDim.x) {
            float4 v = wv[i];
            ushort4 o;
            o.x = (v.x >= thr) ? 0x3F80u : ((v.x <= -thr) ? 0xBF80u : 0u);
            o.y = (v.y >= thr) ? 0x3F80u : ((v.y <= -thr) ? 0xBF80u : 0u);
            o.z = (v.z >= thr) ? 0x3F80u : ((v.z <= -thr) ? 0xBF80u : 0u);
            o.w = (v.w >= thr) ? 0x3F80u : ((v.w <= -thr) ? 0xBF80u : 0u);
            qv[i] = o;
        }
    }
}

// ---------------------------------------------------------------------------
// Kernel 2: x fp32 -> bf16 (RNE), 8 elems/thread.
// ---------------------------------------------------------------------------
__global__ __launch_bounds__(256) void convert_x_kernel(
    const float* __restrict__ x, unsigned short* __restrict__ xb, long n)
{
    long i = ((long)blockIdx.x * blockDim.x + threadIdx.x) * 8;
    if (i + 8 > n) return;
    float4 a = *(const float4*)(x + i);
    float4 b = *(const float4*)(x + i + 4);
    ushort4 lo, hi;
    lo.x = f2bf(a.x); lo.y = f2bf(a.y); lo.z = f2bf(a.z); lo.w = f2bf(a.w);
    hi.x = f2bf(b.x); hi.y = f2bf(b.y); hi.z = f2bf(b.z); hi.w = f2bf(b.w);
    *(ushort4*)(xb + i)     = lo;
    *(ushort4*)(xb + i + 4) = hi;
}

// ---------------------------------------------------------------------------
// Kernel 3: 256x256 8-phase bf16 GEMM (T2+T3+T4+T5).
//   out[m][n] = scale[n] * sum_k Xb[m][k]*Qb[n][k] + bias[n]
// 512 thr = 8 waves (2M x 4N); per-wave 128x64 out = acc[8][4] 16x16x32 MFMA.
// LDS 128 KiB: 2 dbuf x {A 256x64, B 256x64} bf16; 4 half-tile stages/K-tile
// (order B0,B1,A0,A1), issued DELTA=6 half-tiles ahead; counted vmcnt(4) once
// per K-tile; raw s_barriers (no vmcnt drain); setprio(1) around MFMA.
// Both-sides XOR chunk swizzle: LDS slot s of row r holds global chunk s^(r&7).
// ---------------------------------------------------------------------------
#define BM 256
#define BN 256
#define BK 64

__global__ __launch_bounds__(512, 2) void gemm256_kernel(
    const unsigned short* __restrict__ Xb,   // [M][K] bf16 bits
    const unsigned short* __restrict__ Qb,   // [N][K] bf16 bits
    const float* __restrict__ scale,
    const float* __restrict__ bias,
    float* __restrict__ out, int M, int N, int K)
{
    __shared__ __align__(16) char lds[131072];

    const int tid  = threadIdx.x;
    const int lane = tid & 63;
    const int wid  = tid >> 6;       // 0..7
    const int wm   = wid >> 2;       // 0..1  (M half of tile)
    const int wn   = wid & 3;        // 0..3  (N quarter)
    const int kh   = lane >> 4;      // 0..3
    const int lr   = lane & 15;

    // XCD-bijective swizzle (grid % 8 == 0 guaranteed by host gate)
    int bid = blockIdx.x;
    const int nwg = gridDim.x;
    if ((nwg & 7) == 0) { const int cpx = nwg >> 3; bid = (bid & 7) * cpx + (bid >> 3); }
    const int nbn = N / BN;
    const int tm = bid / nbn, tn = bid % nbn;
    const int arow0 = tm * BM;
    const int brow0 = tn * BN;
    const int NT = K / BK;

    const int ci0 = tid, ci1 = 512 + tid;

    // stage half-tile h: K-tile T=h>>2, region rho=h&3 (0:B0 1:B1 2:A0 3:A1)
    auto stage = [&](int h) {
        if (h >= 4 * NT) return;
        const int T = h >> 2, rho = h & 3;
        const int matB = (rho < 2) ? 1 : 0;
        const int hh = rho & 1;
        const unsigned ldsbase = (unsigned)((T & 1) * 65536 + matB * 32768 + hh * 16384);
        const unsigned short* src = matB ? Qb : Xb;
        const int row0 = (matB ? brow0 : arow0) + hh * 128;
        const int k0 = T * BK;
        {
            const int rp = ci0 >> 3, s = ci0 & 7;
            const unsigned short* g = src + (size_t)(row0 + rp) * K + k0 + ((s ^ (rp & 7)) << 3);
            __builtin_amdgcn_global_load_lds(GLOBAL_CAST(g), LDS_CAST(lds + ldsbase + ci0 * 16), 16, 0, 0);
        }
        {
            const int rp = ci1 >> 3, s = ci1 & 7;
            const unsigned short* g = src + (size_t)(row0 + rp) * K + k0 + ((s ^ (rp & 7)) << 3);
            __builtin_amdgcn_global_load_lds(GLOBAL_CAST(g), LDS_CAST(lds + ldsbase + ci1 * 16), 16, 0, 0);
        }
    };

    auto rdA = [&](unsigned abase, int mrow, int cc) -> bf16x8 {
        const int c = kh + cc * 4;
        return *(const bf16x8*)(lds + abase + mrow * 128 + ((c ^ (mrow & 7)) << 4));
    };
    auto rdB = [&](unsigned bbase, int nrow, int cc) -> bf16x8 {
        const int c = kh + cc * 4;
        return *(const bf16x8*)(lds + bbase + nrow * 128 + ((c ^ (nrow & 7)) << 4));
    };

    #define SYNC() do { __builtin_amdgcn_sched_barrier(0); \
                        __builtin_amdgcn_s_barrier(); \
                        __builtin_amdgcn_sched_barrier(0); } while (0)

    f32x4 acc[8][4] = {};
    bf16x8 a[2][4];        // [cc][mf-in-half] — time-shared between M halves
    bf16x8 b[2][2][2];     // [nhalf][cc][nf-in-half]

    // prologue: K-tile0 {B0,B1,A0,A1} + K-tile1 {B0,B1}; leave 2 half-tiles in flight
    for (int h = 0; h < 6; ++h) stage(h);
    asm volatile("s_waitcnt vmcnt(4)" ::: "memory");
    SYNC();

    for (int t = 0; t < NT; ++t) {
        const unsigned abase = (unsigned)((t & 1) * 65536);
        const unsigned bbase = abase + 32768u;
        const int h0 = 4 * t + 6;

        // ---- phase 0: read a-lo + b-lo (12); MFMA m-lo x n-lo ----
        #pragma unroll
        for (int cc = 0; cc < 2; ++cc) {
            #pragma unroll
            for (int mf = 0; mf < 4; ++mf) a[cc][mf] = rdA(abase, wm * 128 + mf * 16 + lr, cc);
            #pragma unroll
            for (int nf = 0; nf < 2; ++nf) b[0][cc][nf] = rdB(bbase, wn * 64 + nf * 16 + lr, cc);
        }
        stage(h0 + 0);
        SYNC();
        __builtin_amdgcn_s_setprio(1);
        #pragma unroll
        for (int mf = 0; mf < 4; ++mf)
            #pragma unroll
            for (int nf = 0; nf < 2; ++nf)
                #pragma unroll
                for (int cc = 0; cc < 2; ++cc)
                    acc[mf][nf] = __builtin_amdgcn_mfma_f32_16x16x32_bf16(a[cc][mf], b[0][cc][nf], acc[mf][nf], 0, 0, 0);
        __builtin_amdgcn_s_setprio(0);
        SYNC();

        // ---- phase 1: read b-hi (4); MFMA m-lo x n-hi ----
        #pragma unroll
        for (int cc = 0; cc < 2; ++cc)
            #pragma unroll
            for (int nf = 0; nf < 2; ++nf) b[1][cc][nf] = rdB(bbase, wn * 64 + 32 + nf * 16 + lr, cc);
        stage(h0 + 1);
        SYNC();
        __builtin_amdgcn_s_setprio(1);
        #pragma unroll
        for (int mf = 0; mf < 4; ++mf)
            #pragma unroll
            for (int nf = 0; nf < 2; ++nf)
                #pragma unroll
                for (int cc = 0; cc < 2; ++cc)
                    acc[mf][2 + nf] = __builtin_amdgcn_mfma_f32_16x16x32_bf16(a[cc][mf], b[1][cc][nf], acc[mf][2 + nf], 0, 0, 0);
        __builtin_amdgcn_s_setprio(0);
        SYNC();

        // ---- phase 2: read a-hi (8, overwrite a); MFMA m-hi x n-hi ----
        #pragma unroll
        for (int cc = 0; cc < 2; ++cc)
            #pragma unroll
            for (int mf = 0; mf < 4; ++mf) a[cc][mf] = rdA(abase, wm * 128 + 64 + mf * 16 + lr, cc);
        stage(h0 + 2);
        SYNC();
        __builtin_amdgcn_s_setprio(1);
        #pragma unroll
        for (int mf = 0; mf < 4; ++mf)
            #pragma unroll
            for (int nf = 0; nf < 2; ++nf)
                #pragma unroll
                for (int cc = 0; cc < 2; ++cc)
                    acc[4 + mf][2 + nf] = __builtin_amdgcn_mfma_f32_16x16x32_bf16(a[cc][mf], b[1][cc][nf], acc[4 + mf][2 + nf], 0, 0, 0);
        __builtin_amdgcn_s_setprio(0);
        SYNC();

        // ---- phase 3: no reads; MFMA m-hi x n-lo; counted vmcnt ----
        stage(h0 + 3);
        SYNC();
        __builtin_amdgcn_s_setprio(1);
        #pragma unroll
        for (int mf = 0; mf < 4; ++mf)
            #pragma unroll
            for (int nf = 0; nf < 2; ++nf)
                #pragma unroll
                for (int cc = 0; cc < 2; ++cc)
                    acc[4 + mf][nf] = __builtin_amdgcn_mfma_f32_16x16x32_bf16(a[cc][mf], b[0][cc][nf], acc[4 + mf][nf], 0, 0, 0);
        __builtin_amdgcn_s_setprio(0);
        if (t < NT - 2) { asm volatile("s_waitcnt vmcnt(4)" ::: "memory"); }
        else            { asm volatile("s_waitcnt vmcnt(0)" ::: "memory"); }
        SYNC();
    }
    #undef SYNC

    // epilogue: out = scale[n]*acc + bias[n]; D layout col=lane&15, row=(lane>>4)*4+r
    #pragma unroll
    for (int nf = 0; nf < 4; ++nf) {
        const int gn = brow0 + wn * 64 + nf * 16 + lr;
        const float sc = scale[gn];
        const float bs = bias[gn];
        #pragma unroll
        for (int mf = 0; mf < 8; ++mf) {
            const size_t gm = (size_t)arow0 + wm * 128 + mf * 16 + kh * 4;
            #pragma unroll
            for (int r = 0; r < 4; ++r)
                out[(gm + r) * (size_t)N + gn] = acc[mf][nf][r] * sc + bs;
        }
    }
}

// ---------------------------------------------------------------------------
// Fallback: fp32 smem-tiled GEMM, quantize on the fly.
// ---------------------------------------------------------------------------
__global__ __launch_bounds__(256) void fb_gemm_kernel(
    const float* __restrict__ X, const float* __restrict__ W,
    const float* __restrict__ scale, const float* __restrict__ bias,
    float* __restrict__ out, int M, int N, int K)
{
    __shared__ float xs[16][16];
    __shared__ float qs[16][17];
    const int tx = threadIdx.x & 15, ty = threadIdx.x >> 4;
    const int m = blockIdx.y * 16 + ty;
    const int n = blockIdx.x * 16 + tx;
    const int nrow = blockIdx.x * 16 + ty;
    const int mL = min(m, M - 1);
    const int nrowL = min(nrow, N - 1);
    const float thr = scale[nrowL] * 0.75f;
    float acc = 0.f;
    for (int k0 = 0; k0 < K; k0 += 16) {
        xs[ty][tx] = X[(size_t)mL * K + k0 + tx];
        const float w = W[(size_t)nrowL * K + k0 + tx];
        qs[ty][tx] = (w >= thr) ? 1.f : ((w <= -thr) ? -1.f : 0.f);
        __syncthreads();
        #pragma unroll
        for (int kk = 0; kk < 16; ++kk) acc += xs[ty][kk] * qs[tx][kk];
        __syncthreads();
    }
    if (m < M && n < N) out[(size_t)m * N + n] = scale[n] * acc + bias[n];
}

// ---------------------------------------------------------------------------
extern "C" void kernel_launch(void* const* d_in, const int* in_sizes, int n_in,
                              void* d_out, int out_size, void* d_ws, size_t ws_size,
                              hipStream_t stream)
{
    const float* x    = (const float*)d_in[0];
    const float* w    = (const float*)d_in[1];
    const float* bias = (const float*)d_in[2];
    float* out = (float*)d_out;

    const int N = in_sizes[2];             // OUT
    const int K = in_sizes[1] / N;         // IN
    const int M = in_sizes[0] / K;         // B

    const size_t scaleBytes = (size_t)N * sizeof(float);
    const size_t qOff = (scaleBytes + 255) & ~(size_t)255;
    const size_t xOff = qOff + (size_t)N * K * sizeof(unsigned short);
    const size_t need = xOff + (size_t)M * K * sizeof(unsigned short);

    float* scale = (float*)d_ws;

    const bool fast = (ws_size >= need) &&
                      (M % BM == 0) && (N % BN == 0) && (K % BK == 0) &&
                      (((M / BM) * (N / BN)) % 8 == 0);

    if (fast) {
        unsigned short* q  = (unsigned short*)((char*)d_ws + qOff);
        unsigned short* xb = (unsigned short*)((char*)d_ws + xOff);

        scale_quant_kernel<<<N, 256, 0, stream>>>(w, scale, q, K);

        const long nx = (long)M * K;
        const int cvtBlocks = (int)((nx + 2047) / 2048);
        convert_x_kernel<<<cvtBlocks, 256, 0, stream>>>(x, xb, nx);

        const int grid = (M / BM) * (N / BN);
        gemm256_kernel<<<grid, 512, 0, stream>>>(xb, q, scale, bias, out, M, N, K);
    } else {
        scale_quant_kernel<<<N, 256, 0, stream>>>(w, scale, nullptr, K);
        dim3 g((N + 15) / 16, (M + 15) / 16);
        fb_gemm_kernel<<<g, 256, 0, stream>>>(x, w, scale, bias, out, M, N, K);
    }
}

// Round 3
// 295.898 us; speedup vs baseline: 1.2442x; 1.0103x over previous
//
#include <hip/hip_runtime.h>
#include <hip/hip_bf16.h>

typedef __attribute__((ext_vector_type(8))) short bf16x8;
typedef __attribute__((ext_vector_type(4))) float f32x4;

#define GLOBAL_CAST(p) (const __attribute__((address_space(1))) void*)(p)
#define LDS_CAST(p)    (__attribute__((address_space(3))) void*)(p)

static __device__ __forceinline__ unsigned short f2bf(float f) {
    union { float f; unsigned int u; } v; v.f = f;
    unsigned int u = v.u;
    unsigned int r = (u + 0x7FFFu + ((u >> 16) & 1u)) >> 16;   // RNE
    return (unsigned short)r;
}

// ---------------------------------------------------------------------------
// Kernel 1: per-row scale = max(mean(|w|), eps); q = ternary(w) as bf16 bits.
// ---------------------------------------------------------------------------
__global__ __launch_bounds__(256) void scale_quant_kernel(
    const float* __restrict__ w, float* __restrict__ scale,
    unsigned short* __restrict__ q, int K)
{
    const int row = blockIdx.x;
    const int tid = threadIdx.x;
    const float* wrow = w + (size_t)row * K;

    float s = 0.f;
    const int nvec = K >> 2;
    const float4* wv = (const float4*)wrow;
    for (int i = tid; i < nvec; i += blockDim.x) {
        float4 v = wv[i];
        s += fabsf(v.x) + fabsf(v.y) + fabsf(v.z) + fabsf(v.w);
    }
    #pragma unroll
    for (int off = 32; off > 0; off >>= 1) s += __shfl_down(s, off);

    __shared__ float red[4];
    const int lane = tid & 63, wid = tid >> 6;
    if (lane == 0) red[wid] = s;
    __syncthreads();
    const float total = red[0] + red[1] + red[2] + red[3];
    const float sc = fmaxf(total / (float)K, 1e-6f);
    const float thr = sc * 0.75f;
    if (tid == 0) scale[row] = sc;

    if (q != nullptr) {
        ushort4* qv = (ushort4*)(q + (size_t)row * K);
        for (int i = tid; i < nvec; i += blockDim.x) {
            float4 v = wv[i];
            ushort4 o;
            o.x = (v.x >= thr) ? 0x3F80u : ((v.x <= -thr) ? 0xBF80u : 0u);
            o.y = (v.y >= thr) ? 0x3F80u : ((v.y <= -thr) ? 0xBF80u : 0u);
            o.z = (v.z >= thr) ? 0x3F80u : ((v.z <= -thr) ? 0xBF80u : 0u);
            o.w = (v.w >= thr) ? 0x3F80u : ((v.w <= -thr) ? 0xBF80u : 0u);
            qv[i] = o;
        }
    }
}

// ---------------------------------------------------------------------------
// Kernel 2: x fp32 -> bf16 (RNE), 8 elems/thread.
// ---------------------------------------------------------------------------
__global__ __launch_bounds__(256) void convert_x_kernel(
    const float* __restrict__ x, unsigned short* __restrict__ xb, long n)
{
    long i = ((long)blockIdx.x * blockDim.x + threadIdx.x) * 8;
    if (i + 8 > n) return;
    float4 a = *(const float4*)(x + i);
    float4 b = *(const float4*)(x + i + 4);
    ushort4 lo, hi;
    lo.x = f2bf(a.x); lo.y = f2bf(a.y); lo.z = f2bf(a.z); lo.w = f2bf(a.w);
    hi.x = f2bf(b.x); hi.y = f2bf(b.y); hi.z = f2bf(b.z); hi.w = f2bf(b.w);
    *(ushort4*)(xb + i)     = lo;
    *(ushort4*)(xb + i + 4) = hi;
}

// ---------------------------------------------------------------------------
// Kernel 3: 256x256 8-phase bf16 GEMM (T1+T2+T3+T4+T5), strength-reduced.
//   out[m][n] = scale[n] * sum_k Xb[m][k]*Qb[n][k] + bias[n]
// 512 thr = 8 waves (2M x 4N); per-wave 128x64 out = acc[8][4] 16x16x32 MFMA.
// LDS 128 KiB: 2 dbuf x {A 256x64, B 256x64} bf16. Per K-tile 4 phases:
//   ph0: rd a-lo(8)+b-lo(4) | stage A0(t+1) | bar | MFMA mlo*nlo | bar
//   ph1: rd b-hi(4)         | stage A1(t+1) | bar | MFMA mlo*nhi | bar
//   ph2: rd a-hi(8)         | stage B0(t+2) | bar | MFMA mhi*nhi | bar
//   ph3: (none)             | stage B1(t+2) | bar | MFMA mhi*nlo |
//        ptr bumps; counted vmcnt(4); sched_barrier; bar
// Raw barriers (no vmcnt drain, no order pinning). LDS addresses precomputed
// per lane (buffer toggle = OR (t&1)<<16; hi-halves fold to ds offset imm).
// Stage streams = 8 running global pointers, += 128B per K-tile.
// Both-sides XOR chunk swizzle: LDS slot s of row r holds global chunk s^(r&7).
// ---------------------------------------------------------------------------
#define BM 256
#define BN 256
#define BK 64

__global__ __launch_bounds__(512, 2) void gemm256_kernel(
    const unsigned short* __restrict__ Xb,   // [M][K] bf16 bits
    const unsigned short* __restrict__ Qb,   // [N][K] bf16 bits
    const float* __restrict__ scale,
    const float* __restrict__ bias,
    float* __restrict__ out, int M, int N, int K)
{
    __shared__ __align__(16) char lds[131072];

    const int tid  = threadIdx.x;
    const int lane = tid & 63;
    const int wid  = tid >> 6;       // 0..7
    const int wm   = wid >> 2;       // 0..1  (M half of tile)
    const int wn   = wid & 3;        // 0..3  (N quarter)
    const int kh   = lane >> 4;      // 0..3
    const int lr   = lane & 15;

    // XCD-bijective swizzle (grid % 8 == 0 guaranteed by host gate)
    int bid = blockIdx.x;
    const int nwg = gridDim.x;
    if ((nwg & 7) == 0) { const int cpx = nwg >> 3; bid = (bid & 7) * cpx + (bid >> 3); }
    const int nbn = N / BN;
    const int tm = bid / nbn, tn = bid % nbn;
    const int arow0 = tm * BM;
    const int brow0 = tn * BN;
    const int NT = K / BK;

    // ---- precomputed LDS read byte-offsets (buffer 0; toggle via OR tb) ----
    unsigned aoff[2][4], boff[2][2];
    #pragma unroll
    for (int cc = 0; cc < 2; ++cc) {
        const int c = kh + cc * 4;
        #pragma unroll
        for (int mf = 0; mf < 4; ++mf) {
            const int row = wm * 128 + mf * 16 + lr;              // a-lo row
            aoff[cc][mf] = (unsigned)(row * 128 + ((c ^ (row & 7)) << 4));
        }
        #pragma unroll
        for (int nf = 0; nf < 2; ++nf) {
            const int row = wn * 64 + nf * 16 + lr;               // b-lo row
            boff[cc][nf] = (unsigned)(32768 + row * 128 + ((c ^ (row & 7)) << 4));
        }
    }
    // a-hi = +8192 bytes (row+64: same &7 -> same swizzle); b-hi = +4096.

    // ---- stage streams: 8 running global pointers + fixed LDS dest offs ----
    const int r0 = tid >> 3,        c0 = (((tid & 7) ^ (r0 & 7)) << 3);
    const int ci1 = 512 + tid;
    const int r1 = ci1 >> 3,        c1 = (((ci1 & 7) ^ (r1 & 7)) << 3);

    const unsigned short* asrc[2][2];
    const unsigned short* bsrc[2][2];
    unsigned adst[2][2], bdst[2][2];
    #pragma unroll
    for (int hh = 0; hh < 2; ++hh) {
        asrc[hh][0] = Xb + (size_t)(arow0 + hh * 128 + r0) * K + BK + c0;     // tile 1's A
        asrc[hh][1] = Xb + (size_t)(arow0 + hh * 128 + r1) * K + BK + c1;
        bsrc[hh][0] = Qb + (size_t)(brow0 + hh * 128 + r0) * K + 2 * BK + c0; // tile 2's B
        bsrc[hh][1] = Qb + (size_t)(brow0 + hh * 128 + r1) * K + 2 * BK + c1;
        adst[hh][0] = (unsigned)(hh * 16384 + tid * 16);
        adst[hh][1] = (unsigned)(hh * 16384 + ci1 * 16);
        bdst[hh][0] = (unsigned)(32768 + hh * 16384 + tid * 16);
        bdst[hh][1] = (unsigned)(32768 + hh * 16384 + ci1 * 16);
    }

    // ---- prologue: stage T0{A0,A1,B0,B1} + T1{B0,B1} from scratch ----
    {
        const int prT[6]  = {0, 0, 0, 0, 1, 1};
        const int prB[6]  = {0, 0, 1, 1, 1, 1};   // 0 = A, 1 = B
        const int prH[6]  = {0, 1, 0, 1, 0, 1};
        #pragma unroll
        for (int i = 0; i < 6; ++i) {
            const int T = prT[i], matB = prB[i], hh = prH[i];
            const unsigned base = (unsigned)((T & 1) * 65536 + matB * 32768 + hh * 16384);
            const unsigned short* src = matB ? Qb : Xb;
            const int row0 = (matB ? brow0 : arow0) + hh * 128;
            const int k0 = T * BK;
            const unsigned short* g0 = src + (size_t)(row0 + r0) * K + k0 + c0;
            const unsigned short* g1 = src + (size_t)(row0 + r1) * K + k0 + c1;
            __builtin_amdgcn_global_load_lds(GLOBAL_CAST(g0), LDS_CAST(lds + base + tid * 16), 16, 0, 0);
            __builtin_amdgcn_global_load_lds(GLOBAL_CAST(g1), LDS_CAST(lds + base + ci1 * 16), 16, 0, 0);
        }
    }
    asm volatile("s_waitcnt vmcnt(4)" ::: "memory");
    __builtin_amdgcn_sched_barrier(0);
    __builtin_amdgcn_s_barrier();

    f32x4 acc[8][4] = {};
    bf16x8 a[2][4];        // time-shared between M halves
    bf16x8 b0[2][2], b1[2][2];

    #define RDA(cc, mf, EX) (*(const bf16x8*)(lds + (tb | aoff[cc][mf]) + (EX)))
    #define RDB(cc, nf, EX) (*(const bf16x8*)(lds + (tb | boff[cc][nf]) + (EX)))
    #define MFMA16(AR, BR, AI, BJ)                                            \
        _Pragma("unroll")                                                     \
        for (int cc = 0; cc < 2; ++cc)                                        \
            _Pragma("unroll")                                                 \
            for (int mf = 0; mf < 4; ++mf)                                    \
                _Pragma("unroll")                                             \
                for (int nf = 0; nf < 2; ++nf)                                \
                    acc[(AI) + mf][(BJ) + nf] =                               \
                        __builtin_amdgcn_mfma_f32_16x16x32_bf16(              \
                            AR[cc][mf], BR[cc][nf], acc[(AI) + mf][(BJ) + nf], 0, 0, 0);

    for (int t = 0; t < NT; ++t) {
        const unsigned tb = (unsigned)(t & 1) << 16;
        const unsigned ta = tb ^ 0x10000u;
        const bool doA = (t < NT - 1), doB = (t < NT - 2);

        // ---- phase 0 ----
        #pragma unroll
        for (int cc = 0; cc < 2; ++cc) {
            #pragma unroll
            for (int mf = 0; mf < 4; ++mf) a[cc][mf] = RDA(cc, mf, 0);
            #pragma unroll
            for (int nf = 0; nf < 2; ++nf) b0[cc][nf] = RDB(cc, nf, 0);
        }
        if (doA) {
            __builtin_amdgcn_global_load_lds(GLOBAL_CAST(asrc[0][0]), LDS_CAST(lds + (ta | adst[0][0])), 16, 0, 0);
            __builtin_amdgcn_global_load_lds(GLOBAL_CAST(asrc[0][1]), LDS_CAST(lds + (ta | adst[0][1])), 16, 0, 0);
        }
        __builtin_amdgcn_s_barrier();
        __builtin_amdgcn_s_setprio(1);
        MFMA16(a, b0, 0, 0)
        __builtin_amdgcn_s_setprio(0);
        __builtin_amdgcn_s_barrier();

        // ---- phase 1 ----
        #pragma unroll
        for (int cc = 0; cc < 2; ++cc)
            #pragma unroll
            for (int nf = 0; nf < 2; ++nf) b1[cc][nf] = RDB(cc, nf, 4096);
        if (doA) {
            __builtin_amdgcn_global_load_lds(GLOBAL_CAST(asrc[1][0]), LDS_CAST(lds + (ta | adst[1][0])), 16, 0, 0);
            __builtin_amdgcn_global_load_lds(GLOBAL_CAST(asrc[1][1]), LDS_CAST(lds + (ta | adst[1][1])), 16, 0, 0);
        }
        __builtin_amdgcn_s_barrier();
        __builtin_amdgcn_s_setprio(1);
        MFMA16(a, b1, 0, 2)
        __builtin_amdgcn_s_setprio(0);
        __builtin_amdgcn_s_barrier();

        // ---- phase 2 ----
        #pragma unroll
        for (int cc = 0; cc < 2; ++cc)
            #pragma unroll
            for (int mf = 0; mf < 4; ++mf) a[cc][mf] = RDA(cc, mf, 8192);
        if (doB) {
            __builtin_amdgcn_global_load_lds(GLOBAL_CAST(bsrc[0][0]), LDS_CAST(lds + (tb | bdst[0][0])), 16, 0, 0);
            __builtin_amdgcn_global_load_lds(GLOBAL_CAST(bsrc[0][1]), LDS_CAST(lds + (tb | bdst[0][1])), 16, 0, 0);
        }
        __builtin_amdgcn_s_barrier();
        __builtin_amdgcn_s_setprio(1);
        MFMA16(a, b1, 4, 2)
        __builtin_amdgcn_s_setprio(0);
        __builtin_amdgcn_s_barrier();

        // ---- phase 3 ----
        if (doB) {
            __builtin_amdgcn_global_load_lds(GLOBAL_CAST(bsrc[1][0]), LDS_CAST(lds + (tb | bdst[1][0])), 16, 0, 0);
            __builtin_amdgcn_global_load_lds(GLOBAL_CAST(bsrc[1][1]), LDS_CAST(lds + (tb | bdst[1][1])), 16, 0, 0);
        }
        __builtin_amdgcn_s_barrier();
        __builtin_amdgcn_s_setprio(1);
        MFMA16(a, b0, 4, 0)
        __builtin_amdgcn_s_setprio(0);

        // advance stage streams (BK elements = 128 B)
        #pragma unroll
        for (int hh = 0; hh < 2; ++hh) {
            asrc[hh][0] += BK; asrc[hh][1] += BK;
            bsrc[hh][0] += BK; bsrc[hh][1] += BK;
        }
        if (t < NT - 2) { asm volatile("s_waitcnt vmcnt(4)" ::: "memory"); }
        else            { asm volatile("s_waitcnt vmcnt(0)" ::: "memory"); }
        __builtin_amdgcn_sched_barrier(0);
        __builtin_amdgcn_s_barrier();
    }
    #undef RDA
    #undef RDB
    #undef MFMA16

    // epilogue: out = scale[n]*acc + bias[n]; D layout col=lane&15, row=(lane>>4)*4+r
    #pragma unroll
    for (int nf = 0; nf < 4; ++nf) {
        const int gn = brow0 + wn * 64 + nf * 16 + lr;
        const float sc = scale[gn];
        const float bs = bias[gn];
        #pragma unroll
        for (int mf = 0; mf < 8; ++mf) {
            const size_t gm = (size_t)arow0 + wm * 128 + mf * 16 + kh * 4;
            #pragma unroll
            for (int r = 0; r < 4; ++r)
                out[(gm + r) * (size_t)N + gn] = acc[mf][nf][r] * sc + bs;
        }
    }
}

// ---------------------------------------------------------------------------
// Fallback: fp32 smem-tiled GEMM, quantize on the fly.
// ---------------------------------------------------------------------------
__global__ __launch_bounds__(256) void fb_gemm_kernel(
    const float* __restrict__ X, const float* __restrict__ W,
    const float* __restrict__ scale, const float* __restrict__ bias,
    float* __restrict__ out, int M, int N, int K)
{
    __shared__ float xs[16][16];
    __shared__ float qs[16][17];
    const int tx = threadIdx.x & 15, ty = threadIdx.x >> 4;
    const int m = blockIdx.y * 16 + ty;
    const int n = blockIdx.x * 16 + tx;
    const int nrow = blockIdx.x * 16 + ty;
    const int mL = min(m, M - 1);
    const int nrowL = min(nrow, N - 1);
    const float thr = scale[nrowL] * 0.75f;
    float acc = 0.f;
    for (int k0 = 0; k0 < K; k0 += 16) {
        xs[ty][tx] = X[(size_t)mL * K + k0 + tx];
        const float w = W[(size_t)nrowL * K + k0 + tx];
        qs[ty][tx] = (w >= thr) ? 1.f : ((w <= -thr) ? -1.f : 0.f);
        __syncthreads();
        #pragma unroll
        for (int kk = 0; kk < 16; ++kk) acc += xs[ty][kk] * qs[tx][kk];
        __syncthreads();
    }
    if (m < M && n < N) out[(size_t)m * N + n] = scale[n] * acc + bias[n];
}

// ---------------------------------------------------------------------------
extern "C" void kernel_launch(void* const* d_in, const int* in_sizes, int n_in,
                              void* d_out, int out_size, void* d_ws, size_t ws_size,
                              hipStream_t stream)
{
    const float* x    = (const float*)d_in[0];
    const float* w    = (const float*)d_in[1];
    const float* bias = (const float*)d_in[2];
    float* out = (float*)d_out;

    const int N = in_sizes[2];             // OUT
    const int K = in_sizes[1] / N;         // IN
    const int M = in_sizes[0] / K;         // B

    const size_t scaleBytes = (size_t)N * sizeof(float);
    const size_t qOff = (scaleBytes + 255) & ~(size_t)255;
    const size_t xOff = qOff + (size_t)N * K * sizeof(unsigned short);
    const size_t need = xOff + (size_t)M * K * sizeof(unsigned short);

    float* scale = (float*)d_ws;

    const bool fast = (ws_size >= need) &&
                      (M % BM == 0) && (N % BN == 0) && (K % BK == 0) &&
                      (K / BK >= 4) &&
                      (((M / BM) * (N / BN)) % 8 == 0);

    if (fast) {
        unsigned short* q  = (unsigned short*)((char*)d_ws + qOff);
        unsigned short* xb = (unsigned short*)((char*)d_ws + xOff);

        scale_quant_kernel<<<N, 256, 0, stream>>>(w, scale, q, K);

        const long nx = (long)M * K;
        const int cvtBlocks = (int)((nx + 2047) / 2048);
        convert_x_kernel<<<cvtBlocks, 256, 0, stream>>>(x, xb, nx);

        const int grid = (M / BM) * (N / BN);
        gemm256_kernel<<<grid, 512, 0, stream>>>(xb, q, scale, bias, out, M, N, K);
    } else {
        scale_quant_kernel<<<N, 256, 0, stream>>>(w, scale, nullptr, K);
        dim3 g((N + 15) / 16, (M + 15) / 16);
        fb_gemm_kernel<<<g, 256, 0, stream>>>(x, w, scale, bias, out, M, N, K);
    }
}

// Round 4
// 273.276 us; speedup vs baseline: 1.3472x; 1.0828x over previous
//
#include <hip/hip_runtime.h>
#include <hip/hip_bf16.h>

typedef __attribute__((ext_vector_type(8))) short bf16x8;
typedef __attribute__((ext_vector_type(4))) float f32x4;

#define GLOBAL_CAST(p) (const __attribute__((address_space(1))) void*)(p)
#define LDS_CAST(p)    (__attribute__((address_space(3))) void*)(p)

static __device__ __forceinline__ unsigned short f2bf(float f) {
    union { float f; unsigned int u; } v; v.f = f;
    unsigned int u = v.u;
    unsigned int r = (u + 0x7FFFu + ((u >> 16) & 1u)) >> 16;   // RNE
    return (unsigned short)r;
}

// ---------------------------------------------------------------------------
// Kernel 1: per-row scale = max(mean(|w|), eps); q = ternary(w) as bf16 bits.
// ---------------------------------------------------------------------------
__global__ __launch_bounds__(256) void scale_quant_kernel(
    const float* __restrict__ w, float* __restrict__ scale,
    unsigned short* __restrict__ q, int K)
{
    const int row = blockIdx.x;
    const int tid = threadIdx.x;
    const float* wrow = w + (size_t)row * K;

    float s = 0.f;
    const int nvec = K >> 2;
    const float4* wv = (const float4*)wrow;
    for (int i = tid; i < nvec; i += blockDim.x) {
        float4 v = wv[i];
        s += fabsf(v.x) + fabsf(v.y) + fabsf(v.z) + fabsf(v.w);
    }
    #pragma unroll
    for (int off = 32; off > 0; off >>= 1) s += __shfl_down(s, off);

    __shared__ float red[4];
    const int lane = tid & 63, wid = tid >> 6;
    if (lane == 0) red[wid] = s;
    __syncthreads();
    const float total = red[0] + red[1] + red[2] + red[3];
    const float sc = fmaxf(total / (float)K, 1e-6f);
    const float thr = sc * 0.75f;
    if (tid == 0) scale[row] = sc;

    if (q != nullptr) {
        ushort4* qv = (ushort4*)(q + (size_t)row * K);
        for (int i = tid; i < nvec; i += blockDim.x) {
            float4 v = wv[i];
            ushort4 o;
            o.x = (v.x >= thr) ? 0x3F80u : ((v.x <= -thr) ? 0xBF80u : 0u);
            o.y = (v.y >= thr) ? 0x3F80u : ((v.y <= -thr) ? 0xBF80u : 0u);
            o.z = (v.z >= thr) ? 0x3F80u : ((v.z <= -thr) ? 0xBF80u : 0u);
            o.w = (v.w >= thr) ? 0x3F80u : ((v.w <= -thr) ? 0xBF80u : 0u);
            qv[i] = o;
        }
    }
}

// ---------------------------------------------------------------------------
// Kernel 2: x fp32 -> bf16 (RNE), 8 elems/thread.
// ---------------------------------------------------------------------------
__global__ __launch_bounds__(256) void convert_x_kernel(
    const float* __restrict__ x, unsigned short* __restrict__ xb, long n)
{
    long i = ((long)blockIdx.x * blockDim.x + threadIdx.x) * 8;
    if (i + 8 > n) return;
    float4 a = *(const float4*)(x + i);
    float4 b = *(const float4*)(x + i + 4);
    ushort4 lo, hi;
    lo.x = f2bf(a.x); lo.y = f2bf(a.y); lo.z = f2bf(a.z); lo.w = f2bf(a.w);
    hi.x = f2bf(b.x); hi.y = f2bf(b.y); hi.z = f2bf(b.z); hi.w = f2bf(b.w);
    *(ushort4*)(xb + i)     = lo;
    *(ushort4*)(xb + i + 4) = hi;
}

// ---------------------------------------------------------------------------
// Kernel 3: 256x256 bf16 GEMM, 2 barriers per K-tile.
//   out[m][n] = scale[n] * sum_k Xb[m][k]*Qb[n][k] + bias[n]
// 512 thr = 8 waves (2M x 4N); per-wave 128x64 out = acc[8][4] 16x16x32 MFMA.
// LDS 128 KiB: 2 dbuf x {A 256x64, B 256x64} bf16.
// Per K-tile t (reads ONLY from buf tb, DMA writes ONLY into buf ta):
//   section A: stage A0,A1(t+1)->ta | rd b0,a-lo | MFMA q0 |
//              stage B0,B1(t+1)->ta | rd b1      | MFMA q1 | s_barrier
//   section B: rd a-hi | MFMA q2 | MFMA q3 | vmcnt(0) | s_barrier
// No intra-tile cross-wave hazards (write buffer != read buffer), so the two
// long sections let 2 waves/SIMD co-issue ds_read under MFMA.
// Both-sides XOR chunk swizzle: LDS slot s of row r holds global chunk s^(r&7).
// ---------------------------------------------------------------------------
#define BM 256
#define BN 256
#define BK 64

__global__ __launch_bounds__(512, 2) void gemm256_kernel(
    const unsigned short* __restrict__ Xb,   // [M][K] bf16 bits
    const unsigned short* __restrict__ Qb,   // [N][K] bf16 bits
    const float* __restrict__ scale,
    const float* __restrict__ bias,
    float* __restrict__ out, int M, int N, int K)
{
    __shared__ __align__(16) char lds[131072];

    const int tid  = threadIdx.x;
    const int lane = tid & 63;
    const int wid  = tid >> 6;       // 0..7
    const int wm   = wid >> 2;       // 0..1  (M half of tile)
    const int wn   = wid & 3;        // 0..3  (N quarter)
    const int kh   = lane >> 4;      // 0..3
    const int lr   = lane & 15;

    // XCD-bijective swizzle (grid % 8 == 0 guaranteed by host gate)
    int bid = blockIdx.x;
    const int nwg = gridDim.x;
    if ((nwg & 7) == 0) { const int cpx = nwg >> 3; bid = (bid & 7) * cpx + (bid >> 3); }
    const int nbn = N / BN;
    const int tm = bid / nbn, tn = bid % nbn;
    const int arow0 = tm * BM;
    const int brow0 = tn * BN;
    const int NT = K / BK;

    // ---- precomputed LDS read byte-offsets (buffer 0; toggle via OR tb) ----
    unsigned aoff[2][4], boff[2][2];
    #pragma unroll
    for (int cc = 0; cc < 2; ++cc) {
        const int c = kh + cc * 4;
        #pragma unroll
        for (int mf = 0; mf < 4; ++mf) {
            const int row = wm * 128 + mf * 16 + lr;              // a-lo row
            aoff[cc][mf] = (unsigned)(row * 128 + ((c ^ (row & 7)) << 4));
        }
        #pragma unroll
        for (int nf = 0; nf < 2; ++nf) {
            const int row = wn * 64 + nf * 16 + lr;               // b-lo row
            boff[cc][nf] = (unsigned)(32768 + row * 128 + ((c ^ (row & 7)) << 4));
        }
    }
    // a-hi = +8192 bytes (row+64: same &7 -> same swizzle); b-hi = +4096.

    // ---- stage streams: 8 running global pointers + fixed LDS dest offs ----
    const int r0 = tid >> 3,        c0 = (((tid & 7) ^ (r0 & 7)) << 3);
    const int ci1 = 512 + tid;
    const int r1 = ci1 >> 3,        c1 = (((ci1 & 7) ^ (r1 & 7)) << 3);

    const unsigned short* asrc[2][2];
    const unsigned short* bsrc[2][2];
    unsigned adst[2][2], bdst[2][2];
    #pragma unroll
    for (int hh = 0; hh < 2; ++hh) {
        asrc[hh][0] = Xb + (size_t)(arow0 + hh * 128 + r0) * K + BK + c0;   // tile 1's A
        asrc[hh][1] = Xb + (size_t)(arow0 + hh * 128 + r1) * K + BK + c1;
        bsrc[hh][0] = Qb + (size_t)(brow0 + hh * 128 + r0) * K + BK + c0;   // tile 1's B
        bsrc[hh][1] = Qb + (size_t)(brow0 + hh * 128 + r1) * K + BK + c1;
        adst[hh][0] = (unsigned)(hh * 16384 + tid * 16);
        adst[hh][1] = (unsigned)(hh * 16384 + ci1 * 16);
        bdst[hh][0] = (unsigned)(32768 + hh * 16384 + tid * 16);
        bdst[hh][1] = (unsigned)(32768 + hh * 16384 + ci1 * 16);
    }

    // ---- prologue: stage tile 0 {A0,A1,B0,B1} into buffer 0 ----
    #pragma unroll
    for (int hh = 0; hh < 2; ++hh) {
        const int rowA = arow0 + hh * 128, rowB = brow0 + hh * 128;
        const unsigned short* ga0 = Xb + (size_t)(rowA + r0) * K + c0;
        const unsigned short* ga1 = Xb + (size_t)(rowA + r1) * K + c1;
        const unsigned short* gb0 = Qb + (size_t)(rowB + r0) * K + c0;
        const unsigned short* gb1 = Qb + (size_t)(rowB + r1) * K + c1;
        __builtin_amdgcn_global_load_lds(GLOBAL_CAST(ga0), LDS_CAST(lds + adst[hh][0]), 16, 0, 0);
        __builtin_amdgcn_global_load_lds(GLOBAL_CAST(ga1), LDS_CAST(lds + adst[hh][1]), 16, 0, 0);
        __builtin_amdgcn_global_load_lds(GLOBAL_CAST(gb0), LDS_CAST(lds + bdst[hh][0]), 16, 0, 0);
        __builtin_amdgcn_global_load_lds(GLOBAL_CAST(gb1), LDS_CAST(lds + bdst[hh][1]), 16, 0, 0);
    }
    asm volatile("s_waitcnt vmcnt(0)" ::: "memory");
    __builtin_amdgcn_sched_barrier(0);
    __builtin_amdgcn_s_barrier();

    f32x4 acc[8][4] = {};
    bf16x8 a[2][4];        // time-shared between M halves
    bf16x8 b0[2][2], b1[2][2];

    #define RDA(cc, mf, EX) (*(const bf16x8*)(lds + (tb | aoff[cc][mf]) + (EX)))
    #define RDB(cc, nf, EX) (*(const bf16x8*)(lds + (tb | boff[cc][nf]) + (EX)))
    #define MFMA16(AR, BR, AI, BJ)                                            \
        _Pragma("unroll")                                                     \
        for (int cc = 0; cc < 2; ++cc)                                        \
            _Pragma("unroll")                                                 \
            for (int mf = 0; mf < 4; ++mf)                                    \
                _Pragma("unroll")                                             \
                for (int nf = 0; nf < 2; ++nf)                                \
                    acc[(AI) + mf][(BJ) + nf] =                               \
                        __builtin_amdgcn_mfma_f32_16x16x32_bf16(              \
                            AR[cc][mf], BR[cc][nf], acc[(AI) + mf][(BJ) + nf], 0, 0, 0);

    for (int t = 0; t < NT; ++t) {
        const unsigned tb = (unsigned)(t & 1) << 16;
        const unsigned ta = tb ^ 0x10000u;
        const bool doS = (t < NT - 1);

        // ================= section A =================
        if (doS) {
            #pragma unroll
            for (int hh = 0; hh < 2; ++hh) {
                __builtin_amdgcn_global_load_lds(GLOBAL_CAST(asrc[hh][0]), LDS_CAST(lds + (ta | adst[hh][0])), 16, 0, 0);
                __builtin_amdgcn_global_load_lds(GLOBAL_CAST(asrc[hh][1]), LDS_CAST(lds + (ta | adst[hh][1])), 16, 0, 0);
            }
        }
        #pragma unroll
        for (int cc = 0; cc < 2; ++cc) {
            #pragma unroll
            for (int nf = 0; nf < 2; ++nf) b0[cc][nf] = RDB(cc, nf, 0);
            #pragma unroll
            for (int mf = 0; mf < 4; ++mf) a[cc][mf] = RDA(cc, mf, 0);
        }
        __builtin_amdgcn_s_setprio(1);
        MFMA16(a, b0, 0, 0)
        __builtin_amdgcn_s_setprio(0);

        if (doS) {
            #pragma unroll
            for (int hh = 0; hh < 2; ++hh) {
                __builtin_amdgcn_global_load_lds(GLOBAL_CAST(bsrc[hh][0]), LDS_CAST(lds + (ta | bdst[hh][0])), 16, 0, 0);
                __builtin_amdgcn_global_load_lds(GLOBAL_CAST(bsrc[hh][1]), LDS_CAST(lds + (ta | bdst[hh][1])), 16, 0, 0);
            }
        }
        #pragma unroll
        for (int cc = 0; cc < 2; ++cc)
            #pragma unroll
            for (int nf = 0; nf < 2; ++nf) b1[cc][nf] = RDB(cc, nf, 4096);
        __builtin_amdgcn_s_setprio(1);
        MFMA16(a, b1, 0, 2)
        __builtin_amdgcn_s_setprio(0);

        __builtin_amdgcn_s_barrier();

        // ================= section B =================
        #pragma unroll
        for (int cc = 0; cc < 2; ++cc)
            #pragma unroll
            for (int mf = 0; mf < 4; ++mf) a[cc][mf] = RDA(cc, mf, 8192);
        __builtin_amdgcn_s_setprio(1);
        MFMA16(a, b1, 4, 2)
        MFMA16(a, b0, 4, 0)
        __builtin_amdgcn_s_setprio(0);

        // advance stage streams (BK elements = 128 B)
        #pragma unroll
        for (int hh = 0; hh < 2; ++hh) {
            asrc[hh][0] += BK; asrc[hh][1] += BK;
            bsrc[hh][0] += BK; bsrc[hh][1] += BK;
        }
        asm volatile("s_waitcnt vmcnt(0)" ::: "memory");
        __builtin_amdgcn_sched_barrier(0);
        __builtin_amdgcn_s_barrier();
    }
    #undef RDA
    #undef RDB
    #undef MFMA16

    // epilogue: out = scale[n]*acc + bias[n]; D layout col=lane&15, row=(lane>>4)*4+r
    #pragma unroll
    for (int nf = 0; nf < 4; ++nf) {
        const int gn = brow0 + wn * 64 + nf * 16 + lr;
        const float sc = scale[gn];
        const float bs = bias[gn];
        #pragma unroll
        for (int mf = 0; mf < 8; ++mf) {
            const size_t gm = (size_t)arow0 + wm * 128 + mf * 16 + kh * 4;
            #pragma unroll
            for (int r = 0; r < 4; ++r)
                out[(gm + r) * (size_t)N + gn] = acc[mf][nf][r] * sc + bs;
        }
    }
}

// ---------------------------------------------------------------------------
// Fallback: fp32 smem-tiled GEMM, quantize on the fly.
// ---------------------------------------------------------------------------
__global__ __launch_bounds__(256) void fb_gemm_kernel(
    const float* __restrict__ X, const float* __restrict__ W,
    const float* __restrict__ scale, const float* __restrict__ bias,
    float* __restrict__ out, int M, int N, int K)
{
    __shared__ float xs[16][16];
    __shared__ float qs[16][17];
    const int tx = threadIdx.x & 15, ty = threadIdx.x >> 4;
    const int m = blockIdx.y * 16 + ty;
    const int n = blockIdx.x * 16 + tx;
    const int nrow = blockIdx.x * 16 + ty;
    const int mL = min(m, M - 1);
    const int nrowL = min(nrow, N - 1);
    const float thr = scale[nrowL] * 0.75f;
    float acc = 0.f;
    for (int k0 = 0; k0 < K; k0 += 16) {
        xs[ty][tx] = X[(size_t)mL * K + k0 + tx];
        const float w = W[(size_t)nrowL * K + k0 + tx];
        qs[ty][tx] = (w >= thr) ? 1.f : ((w <= -thr) ? -1.f : 0.f);
        __syncthreads();
        #pragma unroll
        for (int kk = 0; kk < 16; ++kk) acc += xs[ty][kk] * qs[tx][kk];
        __syncthreads();
    }
    if (m < M && n < N) out[(size_t)m * N + n] = scale[n] * acc + bias[n];
}

// ---------------------------------------------------------------------------
extern "C" void kernel_launch(void* const* d_in, const int* in_sizes, int n_in,
                              void* d_out, int out_size, void* d_ws, size_t ws_size,
                              hipStream_t stream)
{
    const float* x    = (const float*)d_in[0];
    const float* w    = (const float*)d_in[1];
    const float* bias = (const float*)d_in[2];
    float* out = (float*)d_out;

    const int N = in_sizes[2];             // OUT
    const int K = in_sizes[1] / N;         // IN
    const int M = in_sizes[0] / K;         // B

    const size_t scaleBytes = (size_t)N * sizeof(float);
    const size_t qOff = (scaleBytes + 255) & ~(size_t)255;
    const size_t xOff = qOff + (size_t)N * K * sizeof(unsigned short);
    const size_t need = xOff + (size_t)M * K * sizeof(unsigned short);

    float* scale = (float*)d_ws;

    const bool fast = (ws_size >= need) &&
                      (M % BM == 0) && (N % BN == 0) && (K % BK == 0) &&
                      (K / BK >= 4) &&
                      (((M / BM) * (N / BN)) % 8 == 0);

    if (fast) {
        unsigned short* q  = (unsigned short*)((char*)d_ws + qOff);
        unsigned short* xb = (unsigned short*)((char*)d_ws + xOff);

        scale_quant_kernel<<<N, 256, 0, stream>>>(w, scale, q, K);

        const long nx = (long)M * K;
        const int cvtBlocks = (int)((nx + 2047) / 2048);
        convert_x_kernel<<<cvtBlocks, 256, 0, stream>>>(x, xb, nx);

        const int grid = (M / BM) * (N / BN);
        gemm256_kernel<<<grid, 512, 0, stream>>>(xb, q, scale, bias, out, M, N, K);
    } else {
        scale_quant_kernel<<<N, 256, 0, stream>>>(w, scale, nullptr, K);
        dim3 g((N + 15) / 16, (M + 15) / 16);
        fb_gemm_kernel<<<g, 256, 0, stream>>>(x, w, scale, bias, out, M, N, K);
    }
}